// Round 4
// baseline (102.199 us; speedup 1.0000x reference)
//
#include <hip/hip_runtime.h>
#include <hip/hip_cooperative_groups.h>

namespace cg = cooperative_groups;

// Problem constants (B=2, C=3, D=64, H=128, W=128)
static constexpr int kS   = 64 * 128 * 128;  // spatial size per (b,c) = 1048576
static constexpr int kB   = 2;
static constexpr int kC   = 3;
static constexpr int kNV  = kB * kS;         // voxels over (B,D,H,W) = 2097152
static constexpr int kNV4 = kNV / 4;         // float4 groups = 524288

static constexpr int BLOCKS  = 1024;         // 4 blocks/CU, co-resident (coop)
static constexpr int THREADS = 256;
static constexpr int ITERS   = kNV4 / (BLOCKS * THREADS);   // = 2

// Analytic collapses (exact):
//  * dist_maps[:,1] == (argmax_c p_c != 1) ? 1 : 0  (4D EDT over C,D,H,W with
//    C=3: a zero/pos voxel always sits one channel away at 4D dist^2 = 1).
//  * target is one-hot: t2 = 1 - t0 - t1; sum(t) = NV exactly. Hence
//    fp = sum(p) - tp, fn = NV - tp, and the Tversky denominator is
//    0.5*(sum(p) + NV) + 1 — only {surf, sum_p, tp} are accumulated, and
//    target channel 2 is never read (41.9 MB logical reads, L3-resident).

__global__ __launch_bounds__(THREADS) void loss_fused(
    const float* __restrict__ probs,
    const float* __restrict__ target,
    double* __restrict__ partials,   // [BLOCKS][3]: surf, sum_p, tp
    float* __restrict__ out)
{
    int gid = blockIdx.x * THREADS + threadIdx.x;

    // ---- issue ALL loads up front (independent, static-indexed) ----
    float4 P0[ITERS], P1[ITERS], P2[ITERS], T0[ITERS], T1[ITERS];
#pragma unroll
    for (int it = 0; it < ITERS; ++it) {
        int i = gid + it * (BLOCKS * THREADS);
        int v = i << 2;                  // voxel index; float4 never crosses b
        int b = v >> 20;                 // v / kS
        int x = v & (kS - 1);            // v % kS
        size_t base = (size_t)b * kC * kS + (size_t)x;
        P0[it] = *(const float4*)(probs + base);
        P1[it] = *(const float4*)(probs + base + kS);
        P2[it] = *(const float4*)(probs + base + 2 * (size_t)kS);
        T0[it] = *(const float4*)(target + base);
        T1[it] = *(const float4*)(target + base + kS);
    }

    float surf = 0.f, sp = 0.f, tp = 0.f;
#pragma unroll
    for (int it = 0; it < ITERS; ++it) {
        float pa[4] = {P0[it].x, P0[it].y, P0[it].z, P0[it].w};
        float pb[4] = {P1[it].x, P1[it].y, P1[it].z, P1[it].w};
        float pc[4] = {P2[it].x, P2[it].y, P2[it].z, P2[it].w};
        float ta[4] = {T0[it].x, T0[it].y, T0[it].z, T0[it].w};
        float tb[4] = {T1[it].x, T1[it].y, T1[it].z, T1[it].w};
#pragma unroll
        for (int j = 0; j < 4; ++j) {
            float c0 = pa[j], c1 = pb[j], c2 = pc[j];
            // first-index argmax tie-break (strict >)
            int cls = 0; float best = c0;
            if (c1 > best) { best = c1; cls = 1; }
            if (c2 > best) { cls = 2; }
            if (cls != 1) surf += c1;

            sp += c0 + c1 + c2;
            // tp = p0*t0 + p1*t1 + p2*(1-t0-t1)
            tp += c2 + ta[j] * (c0 - c2) + tb[j] * (c1 - c2);
        }
    }

    // wave (64-lane) reduction in double
    double ds = surf, dsp = sp, dtp = tp;
#pragma unroll
    for (int off = 32; off > 0; off >>= 1) {
        ds  += __shfl_down(ds,  off);
        dsp += __shfl_down(dsp, off);
        dtp += __shfl_down(dtp, off);
    }

    __shared__ double sh[4][3];          // 4 waves per block
    int lane = threadIdx.x & 63;
    int wave = threadIdx.x >> 6;
    if (lane == 0) { sh[wave][0] = ds; sh[wave][1] = dsp; sh[wave][2] = dtp; }
    __syncthreads();
    if (threadIdx.x == 0) {
        double a0 = 0, a1 = 0, a2 = 0;
#pragma unroll
        for (int w = 0; w < 4; ++w) { a0 += sh[w][0]; a1 += sh[w][1]; a2 += sh[w][2]; }
        double* p = partials + (size_t)blockIdx.x * 3;
        p[0] = a0; p[1] = a1; p[2] = a2;   // plain store; grid.sync publishes
    }

    cg::this_grid().sync();              // all partials visible device-wide

    if (blockIdx.x == 0) {
        double s = 0, spd = 0, tpd = 0;
        for (int i = threadIdx.x; i < BLOCKS; i += THREADS) {
            const double* p = partials + (size_t)i * 3;
            s += p[0]; spd += p[1]; tpd += p[2];
        }
#pragma unroll
        for (int off = 32; off > 0; off >>= 1) {
            s   += __shfl_down(s,   off);
            spd += __shfl_down(spd, off);
            tpd += __shfl_down(tpd, off);
        }
        __shared__ double sh2[4][3];
        if (lane == 0) { sh2[wave][0] = s; sh2[wave][1] = spd; sh2[wave][2] = tpd; }
        __syncthreads();
        if (threadIdx.x == 0) {
            double a0 = 0, a1 = 0, a2 = 0;
#pragma unroll
            for (int w = 0; w < 4; ++w) { a0 += sh2[w][0]; a1 += sh2[w][1]; a2 += sh2[w][2]; }
            double surface = a0 / (double)kNV;
            // fp = sp - tp, fn = NV - tp => denom = tp + 0.5*fp + 0.5*fn + 1
            double tversky = 1.0 - (a2 + 1.0) / (0.5 * (a1 + (double)kNV) + 1.0);
            out[0] = (float)(surface + tversky);
        }
    }
}

extern "C" void kernel_launch(void* const* d_in, const int* in_sizes, int n_in,
                              void* d_out, int out_size, void* d_ws, size_t ws_size,
                              hipStream_t stream)
{
    const float* probs  = (const float*)d_in[0];
    const float* target = (const float*)d_in[1];
    float* out = (float*)d_out;
    double* partials = (double*)d_ws;    // BLOCKS*3 doubles = 24 KB

    void* args[] = { (void*)&probs, (void*)&target, (void*)&partials, (void*)&out };
    hipLaunchCooperativeKernel((void*)loss_fused, dim3(BLOCKS), dim3(THREADS),
                               args, 0, stream);
}

// Round 5
// 29.329 us; speedup vs baseline: 3.4846x; 3.4846x over previous
//
#include <hip/hip_runtime.h>

// Problem constants (B=2, C=3, D=64, H=128, W=128)
static constexpr int kS   = 64 * 128 * 128;  // spatial size per (b,c) = 1048576
static constexpr int kB   = 2;
static constexpr int kC   = 3;
static constexpr int kNV  = kB * kS;         // voxels over (B,D,H,W) = 2097152
static constexpr int kNV4 = kNV / 4;         // float4 groups = 524288

static constexpr int BLOCKS  = 256;          // 1 block/CU; small atomic tail
static constexpr int THREADS = 1024;         // 16 waves/block
static constexpr int ITERS   = kNV4 / (BLOCKS * THREADS);   // = 2
static constexpr int WAVES   = THREADS / 64;                // = 16

// Analytic collapses (exact):
//  * dist_maps[:,1] == (argmax_c p_c != 1) ? 1 : 0  (4D EDT over C,D,H,W with
//    C=3: a zero/pos voxel always sits one channel away at 4D dist^2 = 1).
//  * target is one-hot: t2 = 1 - t0 - t1; sum(t) = NV exactly. Hence
//    fp = sum(p) - tp, fn = NV - tp, and the Tversky denominator is
//    0.5*(sum(p) + NV) + 1 — only {surf, sum_p, tp} are accumulated, and
//    target channel 2 is never read (41.9 MB logical reads).
//
// Single dispatch: last-block-done finalize (rocPRIM-style). Agent-scope
// release stores publish per-block partials; agent-scope counter RMW elects
// the finalizer; acquire loads dodge stale cross-XCD L2 lines (G16).

__global__ __launch_bounds__(THREADS) void loss_fused(
    const float* __restrict__ probs,
    const float* __restrict__ target,
    double* __restrict__ partials,   // [BLOCKS][3]: surf, sum_p, tp
    unsigned* __restrict__ counter,  // zeroed via hipMemsetAsync each call
    float* __restrict__ out)
{
    int tid = threadIdx.x;
    int gid = blockIdx.x * THREADS + tid;

    // ---- issue ALL loads up front (independent, static-indexed) ----
    float4 P0[ITERS], P1[ITERS], P2[ITERS], T0[ITERS], T1[ITERS];
#pragma unroll
    for (int it = 0; it < ITERS; ++it) {
        int i = gid + it * (BLOCKS * THREADS);
        int v = i << 2;                  // voxel index; float4 never crosses b
        int b = v >> 20;                 // v / kS
        int x = v & (kS - 1);            // v % kS
        size_t base = (size_t)b * kC * kS + (size_t)x;
        P0[it] = *(const float4*)(probs + base);
        P1[it] = *(const float4*)(probs + base + kS);
        P2[it] = *(const float4*)(probs + base + 2 * (size_t)kS);
        T0[it] = *(const float4*)(target + base);
        T1[it] = *(const float4*)(target + base + kS);
    }

    float surf = 0.f, sp = 0.f, tp = 0.f;
#pragma unroll
    for (int it = 0; it < ITERS; ++it) {
        float pa[4] = {P0[it].x, P0[it].y, P0[it].z, P0[it].w};
        float pb[4] = {P1[it].x, P1[it].y, P1[it].z, P1[it].w};
        float pc[4] = {P2[it].x, P2[it].y, P2[it].z, P2[it].w};
        float ta[4] = {T0[it].x, T0[it].y, T0[it].z, T0[it].w};
        float tb[4] = {T1[it].x, T1[it].y, T1[it].z, T1[it].w};
#pragma unroll
        for (int j = 0; j < 4; ++j) {
            float c0 = pa[j], c1 = pb[j], c2 = pc[j];
            // first-index argmax tie-break (strict >)
            int cls = 0; float best = c0;
            if (c1 > best) { best = c1; cls = 1; }
            if (c2 > best) { cls = 2; }
            if (cls != 1) surf += c1;

            sp += c0 + c1 + c2;
            // tp = p0*t0 + p1*t1 + p2*(1-t0-t1)
            tp += c2 + ta[j] * (c0 - c2) + tb[j] * (c1 - c2);
        }
    }

    // wave (64-lane) reduction in double
    double ds = surf, dsp = sp, dtp = tp;
#pragma unroll
    for (int off = 32; off > 0; off >>= 1) {
        ds  += __shfl_down(ds,  off);
        dsp += __shfl_down(dsp, off);
        dtp += __shfl_down(dtp, off);
    }

    __shared__ double sh[WAVES][3];
    __shared__ bool isLast;
    int lane = tid & 63;
    int wave = tid >> 6;
    if (lane == 0) { sh[wave][0] = ds; sh[wave][1] = dsp; sh[wave][2] = dtp; }
    __syncthreads();

    if (tid == 0) {
        double a0 = 0, a1 = 0, a2 = 0;
#pragma unroll
        for (int w = 0; w < WAVES; ++w) { a0 += sh[w][0]; a1 += sh[w][1]; a2 += sh[w][2]; }
        double* p = partials + (size_t)blockIdx.x * 3;
        __hip_atomic_store(&p[0], a0, __ATOMIC_RELEASE, __HIP_MEMORY_SCOPE_AGENT);
        __hip_atomic_store(&p[1], a1, __ATOMIC_RELEASE, __HIP_MEMORY_SCOPE_AGENT);
        __hip_atomic_store(&p[2], a2, __ATOMIC_RELEASE, __HIP_MEMORY_SCOPE_AGENT);
        unsigned old = __hip_atomic_fetch_add(counter, 1u, __ATOMIC_ACQ_REL,
                                              __HIP_MEMORY_SCOPE_AGENT);
        isLast = (old == (unsigned)(BLOCKS - 1));
    }
    __syncthreads();
    if (!isLast) return;

    // ---- elected finalizer block: reduce BLOCKS*3 partials ----
    double s = 0, spd = 0, tpd = 0;
    if (tid < BLOCKS) {
        const double* p = partials + (size_t)tid * 3;
        s   = __hip_atomic_load(&p[0], __ATOMIC_ACQUIRE, __HIP_MEMORY_SCOPE_AGENT);
        spd = __hip_atomic_load(&p[1], __ATOMIC_ACQUIRE, __HIP_MEMORY_SCOPE_AGENT);
        tpd = __hip_atomic_load(&p[2], __ATOMIC_ACQUIRE, __HIP_MEMORY_SCOPE_AGENT);
    }
#pragma unroll
    for (int off = 32; off > 0; off >>= 1) {
        s   += __shfl_down(s,   off);
        spd += __shfl_down(spd, off);
        tpd += __shfl_down(tpd, off);
    }
    __syncthreads();                       // reuse sh[] safely
    if (lane == 0) { sh[wave][0] = s; sh[wave][1] = spd; sh[wave][2] = tpd; }
    __syncthreads();
    if (tid == 0) {
        double a0 = 0, a1 = 0, a2 = 0;
#pragma unroll
        for (int w = 0; w < WAVES; ++w) { a0 += sh[w][0]; a1 += sh[w][1]; a2 += sh[w][2]; }
        double surface = a0 / (double)kNV;
        // fp = sp - tp, fn = NV - tp => denom = tp + 0.5*fp + 0.5*fn + 1
        double tversky = 1.0 - (a2 + 1.0) / (0.5 * (a1 + (double)kNV) + 1.0);
        out[0] = (float)(surface + tversky);
    }
}

extern "C" void kernel_launch(void* const* d_in, const int* in_sizes, int n_in,
                              void* d_out, int out_size, void* d_ws, size_t ws_size,
                              hipStream_t stream)
{
    const float* probs  = (const float*)d_in[0];
    const float* target = (const float*)d_in[1];
    float* out = (float*)d_out;
    double* partials = (double*)d_ws;                       // 256*3 doubles = 6 KB
    unsigned* counter = (unsigned*)((char*)d_ws + BLOCKS * 3 * sizeof(double));

    hipMemsetAsync(counter, 0, sizeof(unsigned), stream);   // 4-byte reset
    loss_fused<<<BLOCKS, THREADS, 0, stream>>>(probs, target, partials, counter, out);
}